// Round 8
// baseline (632.090 us; speedup 1.0000x reference)
//
#include <hip/hip_runtime.h>
#include <math.h>

#define N_NODES 50000
#define N_EDGES 800000
#define NUM_GRAPHS 256
#define NPADROWS 50048   // 1564*32
#define CAP 64           // CSR capacity per node (max observed degree ~35)
#define NHB 64           // counting-sort blocks
#define DCH ((N_NODES + NHB - 1) / NHB)  // nodes per sort block (782)
#define SCLN -1.44269504088896f  // -log2(e): f-side scale, exp2(SCLN*x)=exp(-x)
#define SCLP 1.44269504088896f   // +log2(e): s-side scale
#define C693 0.69314718056f
#define LROW 264         // LDS staging row stride in u16 (528 B)

typedef __attribute__((ext_vector_type(8))) short short8;
typedef __attribute__((ext_vector_type(4))) float f32x4;
typedef __attribute__((ext_vector_type(2))) float f32x2;

__device__ __forceinline__ float fast_rcp(float x) {
#if __has_builtin(__builtin_amdgcn_rcpf)
  return __builtin_amdgcn_rcpf(x);
#else
  return 1.0f / x;
#endif
}
__device__ __forceinline__ float EX2(float x) {
#if __has_builtin(__builtin_amdgcn_exp2f)
  return __builtin_amdgcn_exp2f(x);
#else
  return exp2f(x);
#endif
}
__device__ __forceinline__ float LG2(float x) {
#if __has_builtin(__builtin_amdgcn_logf)
  return __builtin_amdgcn_logf(x);  // log2
#else
  return log2f(x);
#endif
}
// round-to-nearest-even (prep path, cold)
__device__ __forceinline__ unsigned f2bf(float x) {
  unsigned u = __float_as_uint(x);
  return (u + 0x7fffu + ((u >> 16) & 1u)) >> 16;
}
// round-half-up bf16: 1 VALU op
__device__ __forceinline__ unsigned short bfr(float v) {
  return (unsigned short)((__float_as_uint(v) + 0x8000u) >> 16);
}
__device__ __forceinline__ unsigned pkbfr(float lo, float hi) {
  unsigned a = (__float_as_uint(lo) + 0x8000u) >> 16;
  unsigned b = (__float_as_uint(hi) + 0x8000u) & 0xffff0000u;
  return a | b;
}
__device__ __forceinline__ float u2f(unsigned u) { return __uint_as_float(u); }
__device__ __forceinline__ f32x2 mk2(float a, float b) {
  f32x2 r; r.x = a; r.y = b; return r;
}
// unpack u32 holding (lo u16 -> ch0 bf16, hi u16 -> ch1 bf16) to f32x2
__device__ __forceinline__ f32x2 unp(unsigned u) {
  return mk2(u2f(u << 16), u2f(u & 0xffff0000u));
}
// log2(1+t) for t in [0,1], packed f32x2 Horner.
// [R15 post-mortem: gave only -3% not -13% — trans is cheaper than modeled;
//  keeping the poly anyway (it did not regress and frees trans slots).]
__device__ __forceinline__ f32x2 lg2p1(f32x2 t) {
  f32x2 p = __builtin_elementwise_fma(t, (f32x2)0.0439245f, (f32x2)-0.1898214f);
  p = __builtin_elementwise_fma(t, p, (f32x2)0.4115517f);
  p = __builtin_elementwise_fma(t, p, (f32x2)-0.7072504f);
  p = __builtin_elementwise_fma(t, p, (f32x2)1.4415927f);
  return t * p;
}
// msg pair: sigm (exp2 dom, gf pre-scaled -log2e) * softplus (gs pre-scaled +log2e)
// ln2 factor NOT applied here (folded into epilogue pk_fma); acc += rcp(den)*sp_log2.
__device__ __forceinline__ void edge_ch2(f32x2 gf, f32x2 gs, f32x2& acc) {
  f32x2 den = mk2(EX2(gf.x), EX2(gf.y)) + 1.0f;
  f32x2 ts = mk2(EX2(-fabsf(gs.x)), EX2(-fabsf(gs.y)));
  f32x2 sp = lg2p1(ts) + __builtin_elementwise_max(gs, (f32x2)0.0f);
  f32x2 rc = mk2(fast_rcp(den.x), fast_rcp(den.y));
  acc = __builtin_elementwise_fma(rc, sp, acc);
}

// bf16 x rows, ch128 fp32, pos4, and cnt-zero in one pass (64 thr/node)
__global__ void init_x(const int* __restrict__ atoms, const float* __restrict__ pos,
                       const float* __restrict__ emb, float* __restrict__ x128c,
                       unsigned* __restrict__ xbu, float4* __restrict__ pos4,
                       int* __restrict__ cnt) {
  int n = blockIdx.x;
  int t = threadIdx.x;
  int a = atoms[n];
  float2 e = *(const float2*)(emb + (size_t)a * 128 + 2 * t);
  xbu[(size_t)n * 64 + t] = f2bf(e.x) | (f2bf(e.y) << 16);
  if (t == 0) x128c[n] = pos[n * 3 + 2];
  if (t == 1) pos4[n] = make_float4(pos[3 * n], pos[3 * n + 1], pos[3 * n + 2], 0.f);
  if (t == 2) cnt[n] = 0;
}

// B (pre-scaled by SCLN/SCLP) in MFMA fragment order + Wtail (scale*w1, scale*bias).
__global__ void prep_b(const float* __restrict__ Wf, const float* __restrict__ Ws,
                       const float* __restrict__ bfp, const float* __restrict__ bsp,
                       uint4* __restrict__ Bp, float2* __restrict__ Wtail) {
  int idx = blockIdx.x * 256 + threadIdx.x;
  if (idx < 5 * 4 * 9 * 4 * 64) {
    int lane = idx & 63;
    int t = idx >> 6;
    int ks = t & 3; t >>= 2;
    int ct = t % 9; t /= 9;
    int g = t & 3;
    int l = t >> 2;
    const float* W = (g >= 2) ? Ws : Wf;
    float sc = (g < 2) ? SCLN : SCLP;  // scale folded into B -> MFMA acc pre-scaled
    int col = ct * 16 + (lane & 15);
    int kb = ks * 32 + (lane >> 4) * 8;
    unsigned u[4];
#pragma unroll
    for (int p = 0; p < 4; ++p) {
      unsigned lo = 0, hi = 0;
      if (col < 129) {
        int k0 = kb + 2 * p, k1 = k0 + 1;
        int r0 = (g & 1) ? 129 + k0 : k0;
        int r1 = (g & 1) ? 129 + k1 : k1;
        lo = f2bf(sc * W[(size_t)(l * 259 + r0) * 129 + col]);
        hi = f2bf(sc * W[(size_t)(l * 259 + r1) * 129 + col]);
      }
      u[p] = lo | (hi << 16);
    }
    Bp[idx] = make_uint4(u[0], u[1], u[2], u[3]);
  } else {
    int j = idx - 5 * 4 * 9 * 4 * 64;
    if (j >= 5 * 4 * 144) return;
    int c = j % 144;
    int t = j / 144;
    int g = t & 3;
    int l = t >> 2;
    float sc = (g < 2) ? SCLN : SCLP;
    float w1 = 0.0f, bias = 0.0f;
    if (c <= 128) {
      const float* W = (g >= 2) ? Ws : Wf;
      int row = (g & 1) ? 257 : 128;
      w1 = sc * W[(size_t)(l * 259 + row) * 129 + c];
      if (g == 0) bias = SCLN * bfp[l * 129 + c];
      if (g == 2) bias = SCLP * bsp[l * 129 + c];
    }
    Wtail[(l * 4 + g) * 144 + c] = make_float2(w1, bias);
  }
}

// edge CSR build; threads <= N_NODES also emit graph offsets
__global__ void build_csr(const int* __restrict__ ei, const float4* __restrict__ pos4,
                          const int* __restrict__ batch, int* __restrict__ cnt,
                          int2* __restrict__ csr, int* __restrict__ goff) {
  int e = blockIdx.x * 256 + threadIdx.x;
  if (e <= N_NODES) {
    int b = (e < N_NODES) ? batch[e] : NUM_GRAPHS;
    int bp = (e > 0) ? batch[e - 1] : -1;
    for (int g = bp + 1; g <= b; ++g) goff[g] = e;
  }
  if (e >= N_EDGES) return;
  int s = ei[e];
  int d = ei[N_EDGES + e];
  float4 ps = pos4[s];
  float4 pd = pos4[d];
  float dx = ps.x - pd.x, dy = ps.y - pd.y, dz = ps.z - pd.z;
  float ea = sqrtf(dx * dx + dy * dy + dz * dz);
  int p = atomicAdd(&cnt[d], 1);
  if (p < CAP) csr[d * CAP + p] = make_int2(s, __float_as_int(ea));
}

// [R21] counting sort with ZERO global atomics (R20's 50K device-atomics into
// 2 cache lines was 145us of RMW serialization). Confirmed fixed: deg_* gone
// from top-5; edge_agg 76->72.4us, occupancy 66->75%.
__global__ void deg_hist_blk(const int* __restrict__ cnt, int* __restrict__ bcnt) {
  __shared__ int sh[CAP + 1];
  int t = threadIdx.x, b = blockIdx.x;
  if (t <= CAP) sh[t] = 0;
  __syncthreads();
  int a = b * DCH, e = a + DCH;
  if (e > N_NODES) e = N_NODES;
  for (int n = a + t; n < e; n += 256) {
    int d = cnt[n]; if (d > CAP) d = CAP;
    atomicAdd(&sh[d], 1);  // LDS atomic — contention-free at this scale
  }
  __syncthreads();
  if (t <= CAP) bcnt[b * (CAP + 1) + t] = sh[t];
}
// thread d: register-unrolled prefix over NHB blocks (static indices — no
// scratch, loads issue independently) + shared suffix-sum across bins so
// DESCENDING degree gets the low perm slots (long waves launch first).
__global__ void deg_off(const int* __restrict__ bcnt, int* __restrict__ boff) {
  __shared__ int tot[CAP + 1];
  int d = threadIdx.x;
  int c[NHB];
  if (d <= CAP) {
#pragma unroll
    for (int b = 0; b < NHB; ++b) c[b] = bcnt[b * (CAP + 1) + d];
    int run = 0;
#pragma unroll
    for (int b = 0; b < NHB; ++b) { int v = c[b]; c[b] = run; run += v; }
    tot[d] = run;
  }
  __syncthreads();
  if (d <= CAP) {
    int gbase = 0;
    for (int dd = d + 1; dd <= CAP; ++dd) gbase += tot[dd];
#pragma unroll
    for (int b = 0; b < NHB; ++b) boff[b * (CAP + 1) + d] = c[b] + gbase;
  }
}
__global__ void deg_scatter_blk(const int* __restrict__ cnt,
                                const int* __restrict__ boff, int* __restrict__ perm) {
  __shared__ int base[CAP + 1];
  int t = threadIdx.x, b = blockIdx.x;
  if (t <= CAP) base[t] = boff[b * (CAP + 1) + t];
  __syncthreads();
  int a = b * DCH, e = a + DCH;
  if (e > N_NODES) e = N_NODES;
  for (int n = a + t; n < e; n += 256) {
    int d = cnt[n]; if (d > CAP) d = CAP;
    int pos = atomicAdd(&base[d], 1);  // LDS atomic
    perm[pos] = n;
  }
}

// [R22] same work repartitioned over 8 waves (512 thr): wave = group x ct-half
// (hh=0 -> ct 0..4, hh=1 -> ct 5..8). Theory: 4-wave version carried ~170
// VGPR/wave (acc72 + b/bn 72) -> 3 waves/SIMD, and each 9-frag B batch had only
// ~90cy of MFMA to hide ~200-300cy L2 latency. Halving per-wave state (~110
// VGPR) doubles schedulable waves and B-load streams. Same MFMAs, same LDS
// layout, same write order -> bit-identical output.
// [R19] grouped B loads w/ 1-ks prefetch (kept). 32 rows per block.
// u16 row layout (256 u16): [f(2c),f(2c+1),s(2c),s(2c+1)] at c*4 — Pdh dst, Pfs src.
__global__ __launch_bounds__(512) void gemm_mfma(
    const unsigned* __restrict__ xbu, const float* __restrict__ x128c,
    const uint4* __restrict__ Bp, const float2* __restrict__ Wtail,
    unsigned short* __restrict__ Pdh, unsigned short* __restrict__ Pfs,
    unsigned* __restrict__ Pd128c, unsigned* __restrict__ Pc128, int layer) {
  __shared__ short smA[32 * 136];             // A staging, row stride 136 shorts
  __shared__ unsigned short ldsD[32 * LROW];  // dst row image (f+s interleaved)
  __shared__ unsigned short ldsS[32 * LROW];  // src row image
  int n0 = blockIdx.x * 32;
  int tid = threadIdx.x;
  int w = tid >> 6;        // 0..7
  int g = w >> 1;          // group 0..3
  int hh = w & 1;          // ct-half
  int ct0 = hh ? 5 : 0;
  int NCT = hh ? 4 : 5;
  int l = tid & 63;
  int q = l >> 4, c16 = l & 15;
  const short8* Bp8 = (const short8*)Bp;
  const short8* Bq = Bp8 + (size_t)((layer * 4 + g) * 36) * 64 + l;

  // staging: exactly one uint4 per thread, then ks=0 frag batch (flies during
  // the ds_write + barrier).
  int row0 = tid >> 4, cq = tid & 15;
  uint4 st0 = *(const uint4*)(xbu + (size_t)(n0 + row0) * 64 + cq * 4);
  short8 b[5];
#pragma unroll
  for (int i = 0; i < 5; ++i)
    if (i < NCT) b[i] = Bq[(size_t)((ct0 + i) * 4) * 64];
  *(uint4*)(&smA[row0 * 136 + cq * 8]) = st0;
  __syncthreads();

  f32x4 acc[2][5];
#pragma unroll
  for (int rt = 0; rt < 2; ++rt)
#pragma unroll
    for (int i = 0; i < 5; ++i) acc[rt][i] = (f32x4){0.f, 0.f, 0.f, 0.f};
#pragma unroll
  for (int ks = 0; ks < 4; ++ks) {
    short8 a0 = *(const short8*)(&smA[c16 * 136 + (ks * 4 + q) * 8]);
    short8 a1 = *(const short8*)(&smA[(16 + c16) * 136 + (ks * 4 + q) * 8]);
    short8 bn[5];
    if (ks < 3) {
#pragma unroll
      for (int i = 0; i < 5; ++i)
        if (i < NCT) bn[i] = Bq[(size_t)((ct0 + i) * 4 + ks + 1) * 64];
    }
#pragma unroll
    for (int i = 0; i < 5; ++i) {
      if (i < NCT) {
        acc[0][i] = __builtin_amdgcn_mfma_f32_16x16x32_bf16(a0, b[i], acc[0][i], 0, 0, 0);
        acc[1][i] = __builtin_amdgcn_mfma_f32_16x16x32_bf16(a1, b[i], acc[1][i], 0, 0, 0);
      }
    }
    if (ks < 3) {
#pragma unroll
      for (int i = 0; i < 5; ++i)
        if (i < NCT) b[i] = bn[i];
    }
  }
  const float2* Wt = Wtail + (layer * 4 + g) * 144;
  float x128[2][4];
#pragma unroll
  for (int rt = 0; rt < 2; ++rt)
#pragma unroll
    for (int r = 0; r < 4; ++r)
      x128[rt][r] = x128c[n0 + rt * 16 + q * 4 + r];  // contiguous, L1-hit
  unsigned short* ldsO = (g & 1) ? ldsS : ldsD;
  int soff = (g >= 2) ? 2 : 0;
  unsigned short* c128p = (g & 1) ? (unsigned short*)Pc128 : (unsigned short*)Pd128c;
  int c128o = (g >= 2) ? 1 : 0;
#pragma unroll
  for (int i = 0; i < 5; ++i) {
    if (i < NCT) {
      int ct = ct0 + i;
      int col = ct * 16 + c16;
      float2 wb = Wt[col];  // (scale*w1, scale*bias)
#pragma unroll
      for (int rt = 0; rt < 2; ++rt) {
#pragma unroll
        for (int r = 0; r < 4; ++r) {
          int rl = rt * 16 + q * 4 + r;  // local row
          float v = acc[rt][i][r] + fmaf(x128[rt][r], wb.x, wb.y);
          if (col < 128) {
            ldsO[rl * LROW + ((col >> 1) << 2) + soff + (col & 1)] = bfr(v);
          } else if (col == 128) {
            c128p[2 * (size_t)(n0 + rl) + c128o] = bfr(v);
          }
        }
      }
    }
  }
  __syncthreads();
  // coalesced writeback: 2048 16B-chunks (1024 per image), 4 rounds of 512 thr
#pragma unroll
  for (int i = tid; i < 2048; i += 512) {
    int img = i >> 10;
    int c = i & 1023;
    int row = c >> 5, part = c & 31;
    const unsigned short* src = (img ? ldsS : ldsD) + row * LROW + part * 8;
    unsigned short* dst = (img ? Pfs : Pdh) + (size_t)(n0 + row) * 256 + part * 8;
    *(uint4*)dst = *(const uint4*)src;
  }
}

// one wave per dst node (node = perm[wave] — degree-bucketed, R20/R21). Lanes
// 0-31: even edges, 32-63: odd edges; each lane 4 channels via one uint4 gather.
// Depth-1 prefetch [R13 optimum]. Residual carried in bf16 xbu.
// [R15] LG2 -> packed deg-5 poly; ln2 folded into epilogue fma; exec-masked odd tail.
// [R21 accounting: ~325 busy-cy/iter vs ~300 instruction floor — near its
// structure's limit; not the next lever.]
__global__ __launch_bounds__(256) void edge_agg(
    const unsigned short* __restrict__ Pdh, const unsigned short* __restrict__ Pfs,
    const unsigned* __restrict__ Pd128c, const unsigned* __restrict__ Pc128,
    unsigned* __restrict__ xbu, float* __restrict__ x128c, const int* __restrict__ cnt,
    const int2* __restrict__ csr, const float* __restrict__ WfL,
    const float* __restrict__ WsL, const int* __restrict__ perm) {
  int lane = threadIdx.x & 63;
  int half = lane >> 5;
  int l5 = lane & 31;
  int widx = blockIdx.x * 4 + (threadIdx.x >> 6);
  if (widx >= N_NODES) return;
  int nu = __builtin_amdgcn_readfirstlane(perm[widx]);  // wave-uniform -> scalar pipe
  const float* wfl = WfL + 258 * 129;
  const float* wsl = WsL + 258 * 129;
  uint4 pdv = *(const uint4*)(Pdh + (size_t)nu * 256 + 8 * l5);
  f32x2 bfa = unp(pdv.x), bsa = unp(pdv.y), bfb = unp(pdv.z), bsb = unp(pdv.w);
  float2 wfa0 = *(const float2*)(wfl + 4 * l5);
  float2 wfb0 = *(const float2*)(wfl + 4 * l5 + 2);
  float2 wsa0 = *(const float2*)(wsl + 4 * l5);
  float2 wsb0 = *(const float2*)(wsl + 4 * l5 + 2);
  f32x2 wfa = mk2(SCLN * wfa0.x, SCLN * wfa0.y), wfb = mk2(SCLN * wfb0.x, SCLN * wfb0.y);
  f32x2 wsa = mk2(SCLP * wsa0.x, SCLP * wsa0.y), wsb = mk2(SCLP * wsb0.x, SCLP * wsb0.y);
  unsigned pd1 = Pd128c[nu];
  float bfc8 = u2f(pd1 << 16), bsc8 = u2f(pd1 & 0xffff0000u);
  float wfc8 = SCLN * wfl[128], wsc8 = SCLP * wsl[128];
  int m = cnt[nu];
  if (m > CAP) m = CAP;
  const int4* cb4 = (const int4*)(csr + (size_t)nu * CAP);  // wave-uniform pair load
  const uint4* Pfq = (const uint4*)Pfs;
  f32x2 accA = (f32x2)0.0f, accB = (f32x2)0.0f;

#define GATHER(qq) Pfq[(size_t)(half ? qq.z : qq.x) * 32 + l5]
#define COMPUTE(qq, gg)                                                       \
  {                                                                           \
    f32x2 ea_ = (f32x2)__int_as_float(half ? qq.w : qq.y);                    \
    edge_ch2(__builtin_elementwise_fma(ea_, wfa, bfa + unp(gg.x)),            \
             __builtin_elementwise_fma(ea_, wsa, bsa + unp(gg.y)), accA);     \
    edge_ch2(__builtin_elementwise_fma(ea_, wfb, bfb + unp(gg.z)),            \
             __builtin_elementwise_fma(ea_, wsb, bsb + unp(gg.w)), accB);     \
  }

  int Pf = m >> 1;
  int4 qc = make_int4(0, 0, 0, 0);
  uint4 gc = make_uint4(0, 0, 0, 0);
  if (Pf > 0) {
    qc = cb4[0];
    gc = GATHER(qc);
  }
  for (int p = 0; p < Pf; ++p) {
    int4 qn = qc;
    uint4 gn = gc;
    if (p + 1 < Pf) {
      qn = cb4[p + 1];
      gn = GATHER(qn);
    }
    COMPUTE(qc, gc);
    qc = qn;
    gc = gn;
  }
  if ((m & 1) && half == 0) {  // last edge: only half 0 computes it (exec-masked)
    int4 qt = cb4[Pf];
    f32x2 ea_ = (f32x2)__int_as_float(qt.y);
    uint4 gt = Pfq[(size_t)qt.x * 32 + l5];
    edge_ch2(__builtin_elementwise_fma(ea_, wfa, bfa + unp(gt.x)),
             __builtin_elementwise_fma(ea_, wsa, bsa + unp(gt.y)), accA);
    edge_ch2(__builtin_elementwise_fma(ea_, wfb, bfb + unp(gt.z)),
             __builtin_elementwise_fma(ea_, wsb, bsb + unp(gt.w)), accB);
  }
#undef GATHER
#undef COMPUTE

  // combine halves
  accA.x += __shfl_xor(accA.x, 32, 64);
  accA.y += __shfl_xor(accA.y, 32, 64);
  accB.x += __shfl_xor(accB.x, 32, 64);
  accB.y += __shfl_xor(accB.y, 32, 64);

  // channel 128: lanes parallel over edges (deg <= 64), single u32 gather, reduce
  float v2 = 0.f;
  if (lane < m) {
    int2 se = csr[(size_t)nu * CAP + lane];
    float ea = __int_as_float(se.y);
    unsigned pc = Pc128[se.x];
    float f2 = u2f(pc << 16), s2 = u2f(pc & 0xffff0000u);
    float gf2 = fmaf(ea, wfc8, bfc8 + f2);
    float gs2 = fmaf(ea, wsc8, bsc8 + s2);
    float sp2 = LG2(1.0f + EX2(-fabsf(gs2))) + fmaxf(gs2, 0.0f);
    v2 = C693 * fast_rcp(1.0f + EX2(gf2)) * sp2;
  }
#pragma unroll
  for (int off = 32; off; off >>= 1) v2 += __shfl_down(v2, off, 64);

  if (half == 0) {
    uint2 xv = *(const uint2*)(xbu + (size_t)nu * 64 + 2 * l5);
    f32x2 xa = __builtin_elementwise_fma(accA, (f32x2)C693, unp(xv.x));
    f32x2 xb = __builtin_elementwise_fma(accB, (f32x2)C693, unp(xv.y));
    *(uint2*)(xbu + (size_t)nu * 64 + 2 * l5) =
        make_uint2(pkbfr(xa.x, xa.y), pkbfr(xb.x, xb.y));
  }
  if (lane == 0) x128c[nu] += v2;
}

// 4 partial blocks per graph, disjoint writes (no atomics, no pre-zero)
__global__ void pool2(const unsigned* __restrict__ xbu, const float* __restrict__ x128c,
                      const int* __restrict__ goff, float* __restrict__ gpart) {
  int gph = blockIdx.x >> 2;
  int q = blockIdx.x & 3;
  int t = threadIdx.x;
  if (t >= 129) return;
  int s = goff[gph], e = goff[gph + 1];
  int len = e - s;
  int chunk = (len + 3) >> 2;
  int a = s + q * chunk;
  int b = a + chunk; if (b > e) b = e;
  float acc = 0.f;
  if (t < 128) {
    int w = t >> 1, hi = t & 1;
    for (int n = a; n < b; ++n) {
      unsigned u = xbu[(size_t)n * 64 + w];
      acc += hi ? u2f(u & 0xffff0000u) : u2f(u << 16);
    }
  } else {
    for (int n = a; n < b; ++n) acc += x128c[n];
  }
  gpart[(size_t)(gph * 4 + q) * 132 + t] = acc;  // unconditional (ws is poisoned)
}

// fused: partial-sum + mean-divide + fc1 + fc2 + fc3 + out. one block per graph.
// [R16] double-buffered 16-wide independent W loads — was 75us serial-chain, theory
// confirmed (dropped out of top-5).
__global__ void fcout(const float* __restrict__ gpart, const int* __restrict__ goff,
                      const float* __restrict__ Wfc, const float* __restrict__ bfc,
                      const float* __restrict__ Wout, const float* __restrict__ bout,
                      float* __restrict__ out) {
  __shared__ float buf[2][132];
  __shared__ float red[3];
  int i = blockIdx.x;
  int t = threadIdx.x;
  bool act = t < 129;
  int len = goff[i + 1] - goff[i];
  float inv = fast_rcp(fmaxf((float)len, 1.0f));
  if (act) {
    float v = gpart[(size_t)(i * 4 + 0) * 132 + t] + gpart[(size_t)(i * 4 + 1) * 132 + t] +
              gpart[(size_t)(i * 4 + 2) * 132 + t] + gpart[(size_t)(i * 4 + 3) * 132 + t];
    buf[0][t] = v * inv;
  }
  __syncthreads();
  int cur = 0;
#pragma unroll
  for (int l = 0; l < 3; ++l) {
    float s = 0.f;
    if (act) {
      const float* Wl = Wfc + (size_t)l * 129 * 129 + t;
      s = bfc[l * 129 + t];
      float wA[16], wB[16];
      float wlast = Wl[(size_t)128 * 129];  // k=128 tail, issued early
#pragma unroll
      for (int j = 0; j < 16; ++j) wA[j] = Wl[(size_t)j * 129];  // group 0
#pragma unroll
      for (int kb = 0; kb < 128; kb += 16) {
        const int gidx = kb >> 4;  // compile-time under unroll
        float* wc = (gidx & 1) ? wB : wA;
        float* wn = (gidx & 1) ? wA : wB;
        if (kb + 16 < 128) {
#pragma unroll
          for (int j = 0; j < 16; ++j) wn[j] = Wl[(size_t)(kb + 16 + j) * 129];
        }
#pragma unroll
        for (int j = 0; j < 16; ++j) s = fmaf(buf[cur][kb + j], wc[j], s);
      }
      s = fmaf(buf[cur][128], wlast, s);
    }
    __syncthreads();
    if (act) buf[1 - cur][t] = s;
    cur = 1 - cur;
    __syncthreads();
  }
  float p = act ? buf[cur][t] * Wout[t] : 0.f;
#pragma unroll
  for (int off = 32; off; off >>= 1) p += __shfl_down(p, off, 64);
  if ((t & 63) == 0) red[t >> 6] = p;
  __syncthreads();
  if (t == 0) out[i] = red[0] + red[1] + red[2] + bout[0];
}

extern "C" void kernel_launch(void* const* d_in, const int* in_sizes, int n_in,
                              void* d_out, int out_size, void* d_ws, size_t ws_size,
                              hipStream_t stream) {
  const int* atoms = (const int*)d_in[0];
  const float* pos = (const float*)d_in[1];
  const int* ei = (const int*)d_in[2];
  const int* batch = (const int*)d_in[3];
  const float* emb = (const float*)d_in[4];
  const float* Wf = (const float*)d_in[5];
  const float* bfp = (const float*)d_in[6];
  const float* Ws = (const float*)d_in[7];
  const float* bsp = (const float*)d_in[8];
  const float* Wfc = (const float*)d_in[9];
  const float* bfc = (const float*)d_in[10];
  const float* Wout = (const float*)d_in[11];
  const float* bout = (const float*)d_in[12];
  float* outp = (float*)d_out;

  // workspace layout (every array 16B-aligned by construction)
  uint4* Bp = (uint4*)d_ws;                                   // 46080 uint4
  unsigned* xbu = (unsigned*)(Bp + 46080);                    // NPADROWS*64 u32
  unsigned short* Pdh = (unsigned short*)(xbu + (size_t)NPADROWS * 64);  // NPADROWS*256
  unsigned short* Pfs = Pdh + (size_t)NPADROWS * 256;         // NPADROWS*256
  float4* pos4 = (float4*)(Pfs + (size_t)NPADROWS * 256);     // N_NODES float4
  float2* Wtail = (float2*)(pos4 + N_NODES);                  // 5*4*144 float2
  float* x128c = (float*)(Wtail + 5 * 4 * 144);               // NPADROWS f32
  float* gpart = x128c + NPADROWS;                            // 256*4*132 f32
  int* goff = (int*)(gpart + 256 * 4 * 132);                  // 260 (padded)
  int* cnt = goff + 260;                                      // N_NODES (+pad)
  int2* csr = (int2*)(cnt + N_NODES + 4);                     // N_NODES*CAP (16B-aligned)
  unsigned* Pd128c = (unsigned*)(csr + (size_t)N_NODES * CAP);  // NPADROWS u32
  unsigned* Pc128 = Pd128c + NPADROWS;                        // NPADROWS u32
  int* perm = (int*)(Pc128 + NPADROWS);                       // N_NODES (degree-sorted)
  int* bcnt = perm + N_NODES;                                 // NHB*65 per-block hist
  int* boff = bcnt + NHB * (CAP + 1);                         // NHB*65 scatter bases

  init_x<<<N_NODES, 64, 0, stream>>>(atoms, pos, emb, x128c, xbu, pos4, cnt);
  prep_b<<<(5 * 4 * 9 * 4 * 64 + 5 * 4 * 144 + 255) / 256, 256, 0, stream>>>(
      Wf, Ws, bfp, bsp, Bp, Wtail);
  build_csr<<<(N_EDGES + 255) / 256, 256, 0, stream>>>(ei, pos4, batch, cnt, csr, goff);
  deg_hist_blk<<<NHB, 256, 0, stream>>>(cnt, bcnt);
  deg_off<<<1, 128, 0, stream>>>(bcnt, boff);
  deg_scatter_blk<<<NHB, 256, 0, stream>>>(cnt, boff, perm);

  for (int l = 0; l < 5; ++l) {
    gemm_mfma<<<NPADROWS / 32, 512, 0, stream>>>(xbu, x128c, Bp, Wtail, Pdh, Pfs,
                                                 Pd128c, Pc128, l);
    edge_agg<<<(N_NODES + 3) / 4, 256, 0, stream>>>(Pdh, Pfs, Pd128c, Pc128, xbu, x128c,
                                                    cnt, csr,
                                                    Wf + (size_t)l * 259 * 129,
                                                    Ws + (size_t)l * 259 * 129, perm);
  }

  pool2<<<NUM_GRAPHS * 4, 192, 0, stream>>>(xbu, x128c, goff, gpart);
  fcout<<<NUM_GRAPHS, 192, 0, stream>>>(gpart, goff, Wfc, bfc, Wout, bout, outp);
}

// Round 9
// 617.991 us; speedup vs baseline: 1.0228x; 1.0228x over previous
//
#include <hip/hip_runtime.h>
#include <math.h>

#define N_NODES 50000
#define N_EDGES 800000
#define NUM_GRAPHS 256
#define NPADROWS 50048   // 1564*32
#define CAP 64           // CSR capacity per node (max observed degree ~35)
#define NHB 64           // counting-sort blocks
#define DCH ((N_NODES + NHB - 1) / NHB)  // nodes per sort block (782)
#define SCLN -1.44269504088896f  // -log2(e): f-side scale, exp2(SCLN*x)=exp(-x)
#define SCLP 1.44269504088896f   // +log2(e): s-side scale
#define C693 0.69314718056f
#define LROW 264         // LDS staging row stride in u16 (528 B)

typedef __attribute__((ext_vector_type(8))) short short8;
typedef __attribute__((ext_vector_type(4))) float f32x4;
typedef __attribute__((ext_vector_type(2))) float f32x2;

__device__ __forceinline__ float fast_rcp(float x) {
#if __has_builtin(__builtin_amdgcn_rcpf)
  return __builtin_amdgcn_rcpf(x);
#else
  return 1.0f / x;
#endif
}
__device__ __forceinline__ float EX2(float x) {
#if __has_builtin(__builtin_amdgcn_exp2f)
  return __builtin_amdgcn_exp2f(x);
#else
  return exp2f(x);
#endif
}
__device__ __forceinline__ float LG2(float x) {
#if __has_builtin(__builtin_amdgcn_logf)
  return __builtin_amdgcn_logf(x);  // log2
#else
  return log2f(x);
#endif
}
// round-to-nearest-even (prep path, cold)
__device__ __forceinline__ unsigned f2bf(float x) {
  unsigned u = __float_as_uint(x);
  return (u + 0x7fffu + ((u >> 16) & 1u)) >> 16;
}
// round-half-up bf16: 1 VALU op
__device__ __forceinline__ unsigned short bfr(float v) {
  return (unsigned short)((__float_as_uint(v) + 0x8000u) >> 16);
}
__device__ __forceinline__ unsigned pkbfr(float lo, float hi) {
  unsigned a = (__float_as_uint(lo) + 0x8000u) >> 16;
  unsigned b = (__float_as_uint(hi) + 0x8000u) & 0xffff0000u;
  return a | b;
}
__device__ __forceinline__ float u2f(unsigned u) { return __uint_as_float(u); }
__device__ __forceinline__ f32x2 mk2(float a, float b) {
  f32x2 r; r.x = a; r.y = b; return r;
}
// unpack u32 holding (lo u16 -> ch0 bf16, hi u16 -> ch1 bf16) to f32x2
__device__ __forceinline__ f32x2 unp(unsigned u) {
  return mk2(u2f(u << 16), u2f(u & 0xffff0000u));
}
// log2(1+t) for t in [0,1], packed f32x2 Horner.
// [R15: trans ~6cy/op on trans pipe — poly vs 2xLG2 ≈ -4us/dispatch; kept.]
__device__ __forceinline__ f32x2 lg2p1(f32x2 t) {
  f32x2 p = __builtin_elementwise_fma(t, (f32x2)0.0439245f, (f32x2)-0.1898214f);
  p = __builtin_elementwise_fma(t, p, (f32x2)0.4115517f);
  p = __builtin_elementwise_fma(t, p, (f32x2)-0.7072504f);
  p = __builtin_elementwise_fma(t, p, (f32x2)1.4415927f);
  return t * p;
}
// msg pair: sigm (exp2 dom, gf pre-scaled -log2e) * softplus (gs pre-scaled +log2e)
// ln2 factor NOT applied here (folded into epilogue pk_fma); acc += rcp(den)*sp_log2.
// Trans budget/pair: 2 EX2 (sigmoid) + 2 EX2 (softplus) + 2 rcp — minimal for
// this math; edge_agg is near its instruction floor [R21/R22 accounting].
__device__ __forceinline__ void edge_ch2(f32x2 gf, f32x2 gs, f32x2& acc) {
  f32x2 den = mk2(EX2(gf.x), EX2(gf.y)) + 1.0f;
  f32x2 ts = mk2(EX2(-fabsf(gs.x)), EX2(-fabsf(gs.y)));
  f32x2 sp = lg2p1(ts) + __builtin_elementwise_max(gs, (f32x2)0.0f);
  f32x2 rc = mk2(fast_rcp(den.x), fast_rcp(den.y));
  acc = __builtin_elementwise_fma(rc, sp, acc);
}

// [R23] 4 nodes per 256-thread block (was 50K single-wave blocks — pure
// dispatch overhead). Same loads/stores per node.
__global__ __launch_bounds__(256) void init_x(
    const int* __restrict__ atoms, const float* __restrict__ pos,
    const float* __restrict__ emb, float* __restrict__ x128c,
    unsigned* __restrict__ xbu, float4* __restrict__ pos4, int* __restrict__ cnt) {
  int n = blockIdx.x * 4 + (threadIdx.x >> 6);
  if (n >= N_NODES) return;
  int t = threadIdx.x & 63;
  int a = atoms[n];
  float2 e = *(const float2*)(emb + (size_t)a * 128 + 2 * t);
  xbu[(size_t)n * 64 + t] = f2bf(e.x) | (f2bf(e.y) << 16);
  if (t == 0) x128c[n] = pos[n * 3 + 2];
  if (t == 1) pos4[n] = make_float4(pos[3 * n], pos[3 * n + 1], pos[3 * n + 2], 0.f);
  if (t == 2) cnt[n] = 0;
}

// B (pre-scaled by SCLN/SCLP) in MFMA fragment order + Wtail (scale*w1, scale*bias).
__global__ void prep_b(const float* __restrict__ Wf, const float* __restrict__ Ws,
                       const float* __restrict__ bfp, const float* __restrict__ bsp,
                       uint4* __restrict__ Bp, float2* __restrict__ Wtail) {
  int idx = blockIdx.x * 256 + threadIdx.x;
  if (idx < 5 * 4 * 9 * 4 * 64) {
    int lane = idx & 63;
    int t = idx >> 6;
    int ks = t & 3; t >>= 2;
    int ct = t % 9; t /= 9;
    int g = t & 3;
    int l = t >> 2;
    const float* W = (g >= 2) ? Ws : Wf;
    float sc = (g < 2) ? SCLN : SCLP;  // scale folded into B -> MFMA acc pre-scaled
    int col = ct * 16 + (lane & 15);
    int kb = ks * 32 + (lane >> 4) * 8;
    unsigned u[4];
#pragma unroll
    for (int p = 0; p < 4; ++p) {
      unsigned lo = 0, hi = 0;
      if (col < 129) {
        int k0 = kb + 2 * p, k1 = k0 + 1;
        int r0 = (g & 1) ? 129 + k0 : k0;
        int r1 = (g & 1) ? 129 + k1 : k1;
        lo = f2bf(sc * W[(size_t)(l * 259 + r0) * 129 + col]);
        hi = f2bf(sc * W[(size_t)(l * 259 + r1) * 129 + col]);
      }
      u[p] = lo | (hi << 16);
    }
    Bp[idx] = make_uint4(u[0], u[1], u[2], u[3]);
  } else {
    int j = idx - 5 * 4 * 9 * 4 * 64;
    if (j >= 5 * 4 * 144) return;
    int c = j % 144;
    int t = j / 144;
    int g = t & 3;
    int l = t >> 2;
    float sc = (g < 2) ? SCLN : SCLP;
    float w1 = 0.0f, bias = 0.0f;
    if (c <= 128) {
      const float* W = (g >= 2) ? Ws : Wf;
      int row = (g & 1) ? 257 : 128;
      w1 = sc * W[(size_t)(l * 259 + row) * 129 + c];
      if (g == 0) bias = SCLN * bfp[l * 129 + c];
      if (g == 2) bias = SCLP * bsp[l * 129 + c];
    }
    Wtail[(l * 4 + g) * 144 + c] = make_float2(w1, bias);
  }
}

// edge CSR build; threads <= N_NODES also emit graph offsets
__global__ void build_csr(const int* __restrict__ ei, const float4* __restrict__ pos4,
                          const int* __restrict__ batch, int* __restrict__ cnt,
                          int2* __restrict__ csr, int* __restrict__ goff) {
  int e = blockIdx.x * 256 + threadIdx.x;
  if (e <= N_NODES) {
    int b = (e < N_NODES) ? batch[e] : NUM_GRAPHS;
    int bp = (e > 0) ? batch[e - 1] : -1;
    for (int g = bp + 1; g <= b; ++g) goff[g] = e;
  }
  if (e >= N_EDGES) return;
  int s = ei[e];
  int d = ei[N_EDGES + e];
  float4 ps = pos4[s];
  float4 pd = pos4[d];
  float dx = ps.x - pd.x, dy = ps.y - pd.y, dz = ps.z - pd.z;
  float ea = sqrtf(dx * dx + dy * dy + dz * dz);
  int p = atomicAdd(&cnt[d], 1);
  if (p < CAP) csr[d * CAP + p] = make_int2(s, __float_as_int(ea));
}

// [R21] counting sort with ZERO global atomics (R20's 50K device-atomics into
// 2 cache lines was 145us of RMW serialization). Confirmed fixed: deg_* gone
// from top-5; edge_agg 76->72.4us, occupancy 66->75%.
__global__ void deg_hist_blk(const int* __restrict__ cnt, int* __restrict__ bcnt) {
  __shared__ int sh[CAP + 1];
  int t = threadIdx.x, b = blockIdx.x;
  if (t <= CAP) sh[t] = 0;
  __syncthreads();
  int a = b * DCH, e = a + DCH;
  if (e > N_NODES) e = N_NODES;
  for (int n = a + t; n < e; n += 256) {
    int d = cnt[n]; if (d > CAP) d = CAP;
    atomicAdd(&sh[d], 1);  // LDS atomic — contention-free at this scale
  }
  __syncthreads();
  if (t <= CAP) bcnt[b * (CAP + 1) + t] = sh[t];
}
// thread d: register-unrolled prefix over NHB blocks (static indices — no
// scratch, loads issue independently) + shared suffix-sum across bins so
// DESCENDING degree gets the low perm slots (long waves launch first).
__global__ void deg_off(const int* __restrict__ bcnt, int* __restrict__ boff) {
  __shared__ int tot[CAP + 1];
  int d = threadIdx.x;
  int c[NHB];
  if (d <= CAP) {
#pragma unroll
    for (int b = 0; b < NHB; ++b) c[b] = bcnt[b * (CAP + 1) + d];
    int run = 0;
#pragma unroll
    for (int b = 0; b < NHB; ++b) { int v = c[b]; c[b] = run; run += v; }
    tot[d] = run;
  }
  __syncthreads();
  if (d <= CAP) {
    int gbase = 0;
    for (int dd = d + 1; dd <= CAP; ++dd) gbase += tot[dd];
#pragma unroll
    for (int b = 0; b < NHB; ++b) boff[b * (CAP + 1) + d] = c[b] + gbase;
  }
}
__global__ void deg_scatter_blk(const int* __restrict__ cnt,
                                const int* __restrict__ boff, int* __restrict__ perm) {
  __shared__ int base[CAP + 1];
  int t = threadIdx.x, b = blockIdx.x;
  if (t <= CAP) base[t] = boff[b * (CAP + 1) + t];
  __syncthreads();
  int a = b * DCH, e = a + DCH;
  if (e > N_NODES) e = N_NODES;
  for (int n = a + t; n < e; n += 256) {
    int d = cnt[n]; if (d > CAP) d = CAP;
    int pos = atomicAdd(&base[d], 1);  // LDS atomic
    perm[pos] = n;
  }
}

// [R23 = exact R19 revert: 4 waves/256 thr. R22's 8-wave split regressed
// (+1.5us/layer: guard-masked MFMAs, doubled barrier contention, LDS still
// caps residency at 3 blocks/CU). R17/R18 operand-swap also lost. This
// structure is the empirical local optimum: ~36us/layer (B-latency ~2.6
// [R19 delta], HBM r+w floor ~12, rest = barrier+epilogue serial structure).]
// 32 rows x (4 groups x 144 cols) per block; wave w = group w.
// u16 row layout (256 u16): [f(2c),f(2c+1),s(2c),s(2c+1)] at c*4 — Pdh dst, Pfs src.
__global__ __launch_bounds__(256) void gemm_mfma(
    const unsigned* __restrict__ xbu, const float* __restrict__ x128c,
    const uint4* __restrict__ Bp, const float2* __restrict__ Wtail,
    unsigned short* __restrict__ Pdh, unsigned short* __restrict__ Pfs,
    unsigned* __restrict__ Pd128c, unsigned* __restrict__ Pc128, int layer) {
  __shared__ short smA[32 * 136];             // A staging, row stride 136 shorts
  __shared__ unsigned short ldsD[32 * LROW];  // dst row image (f+s interleaved)
  __shared__ unsigned short ldsS[32 * LROW];  // src row image
  int n0 = blockIdx.x * 32;
  int tid = threadIdx.x;
  int g = tid >> 6;
  int l = tid & 63;
  int q = l >> 4, c16 = l & 15;
  const short8* Bp8 = (const short8*)Bp;
  const short8* Bq = Bp8 + (size_t)((layer * 4 + g) * 36) * 64 + l;

  // staging loads + ks=0 fragment batch issued back-to-back: the 9 frag loads
  // fly during the smA ds_writes and the barrier.
  int row0 = tid >> 4, cq = tid & 15;
  uint4 st0 = *(const uint4*)(xbu + (size_t)(n0 + row0) * 64 + cq * 4);
  uint4 st1 = *(const uint4*)(xbu + (size_t)(n0 + 16 + row0) * 64 + cq * 4);
  short8 b[9];
#pragma unroll
  for (int ct = 0; ct < 9; ++ct) b[ct] = Bq[(size_t)(ct * 4) * 64];
  *(uint4*)(&smA[row0 * 136 + cq * 8]) = st0;
  *(uint4*)(&smA[(16 + row0) * 136 + cq * 8]) = st1;
  __syncthreads();

  f32x4 acc[2][9];
#pragma unroll
  for (int rt = 0; rt < 2; ++rt)
#pragma unroll
    for (int ct = 0; ct < 9; ++ct) acc[rt][ct] = (f32x4){0.f, 0.f, 0.f, 0.f};
#pragma unroll
  for (int ks = 0; ks < 4; ++ks) {
    short8 a0 = *(const short8*)(&smA[c16 * 136 + (ks * 4 + q) * 8]);
    short8 a1 = *(const short8*)(&smA[(16 + c16) * 136 + (ks * 4 + q) * 8]);
    short8 bn[9];
    if (ks < 3) {
#pragma unroll
      for (int ct = 0; ct < 9; ++ct) bn[ct] = Bq[(size_t)(ct * 4 + ks + 1) * 64];
    }
#pragma unroll
    for (int ct = 0; ct < 9; ++ct) {
      acc[0][ct] = __builtin_amdgcn_mfma_f32_16x16x32_bf16(a0, b[ct], acc[0][ct], 0, 0, 0);
      acc[1][ct] = __builtin_amdgcn_mfma_f32_16x16x32_bf16(a1, b[ct], acc[1][ct], 0, 0, 0);
    }
    if (ks < 3) {
#pragma unroll
      for (int ct = 0; ct < 9; ++ct) b[ct] = bn[ct];
    }
  }
  const float2* Wt = Wtail + (layer * 4 + g) * 144;
  float x128[2][4];
#pragma unroll
  for (int rt = 0; rt < 2; ++rt)
#pragma unroll
    for (int r = 0; r < 4; ++r)
      x128[rt][r] = x128c[n0 + rt * 16 + q * 4 + r];  // contiguous, L1-hit
  unsigned short* ldsO = (g & 1) ? ldsS : ldsD;
  int soff = (g >= 2) ? 2 : 0;
  unsigned short* c128p = (g & 1) ? (unsigned short*)Pc128 : (unsigned short*)Pd128c;
  int c128o = (g >= 2) ? 1 : 0;
#pragma unroll
  for (int ct = 0; ct < 9; ++ct) {
    int col = ct * 16 + c16;
    float2 wb = Wt[col];  // (scale*w1, scale*bias)
#pragma unroll
    for (int rt = 0; rt < 2; ++rt) {
#pragma unroll
      for (int r = 0; r < 4; ++r) {
        int rl = rt * 16 + q * 4 + r;  // local row
        float v = acc[rt][ct][r] + fmaf(x128[rt][r], wb.x, wb.y);
        if (col < 128) {
          ldsO[rl * LROW + ((col >> 1) << 2) + soff + (col & 1)] = bfr(v);
        } else if (col == 128) {
          c128p[2 * (size_t)(n0 + rl) + c128o] = bfr(v);
        }
      }
    }
  }
  __syncthreads();
  // coalesced writeback: 2048 16B-chunks (1024 per image), 8 rounds of 256 thr
#pragma unroll
  for (int i = tid; i < 2048; i += 256) {
    int img = i >> 10;
    int c = i & 1023;
    int row = c >> 5, part = c & 31;
    const unsigned short* src = (img ? ldsS : ldsD) + row * LROW + part * 8;
    unsigned short* dst = (img ? Pfs : Pdh) + (size_t)(n0 + row) * 256 + part * 8;
    *(uint4*)dst = *(const uint4*)src;
  }
}

// one wave per dst node (node = perm[wave] — degree-bucketed, R20/R21). Lanes
// 0-31: even edges, 32-63: odd edges; each lane 4 channels via one uint4 gather.
// Depth-1 prefetch [R13 optimum]. Residual carried in bf16 xbu.
// [R15] LG2 -> packed deg-5 poly; ln2 folded into epilogue fma; exec-masked odd tail.
// [R21/R22 accounting: ~345 busy-cy/iter, of which ~145cy is the 24 trans-pipe
// ops (6 EX2/rcp per channel-pair = math minimum) — near structure floor.
// FETCH 215MB ≈ 8 XCD x 25.6MB Pfs streaming floor for a random graph.]
__global__ __launch_bounds__(256) void edge_agg(
    const unsigned short* __restrict__ Pdh, const unsigned short* __restrict__ Pfs,
    const unsigned* __restrict__ Pd128c, const unsigned* __restrict__ Pc128,
    unsigned* __restrict__ xbu, float* __restrict__ x128c, const int* __restrict__ cnt,
    const int2* __restrict__ csr, const float* __restrict__ WfL,
    const float* __restrict__ WsL, const int* __restrict__ perm) {
  int lane = threadIdx.x & 63;
  int half = lane >> 5;
  int l5 = lane & 31;
  int widx = blockIdx.x * 4 + (threadIdx.x >> 6);
  if (widx >= N_NODES) return;
  int nu = __builtin_amdgcn_readfirstlane(perm[widx]);  // wave-uniform -> scalar pipe
  const float* wfl = WfL + 258 * 129;
  const float* wsl = WsL + 258 * 129;
  uint4 pdv = *(const uint4*)(Pdh + (size_t)nu * 256 + 8 * l5);
  f32x2 bfa = unp(pdv.x), bsa = unp(pdv.y), bfb = unp(pdv.z), bsb = unp(pdv.w);
  float2 wfa0 = *(const float2*)(wfl + 4 * l5);
  float2 wfb0 = *(const float2*)(wfl + 4 * l5 + 2);
  float2 wsa0 = *(const float2*)(wsl + 4 * l5);
  float2 wsb0 = *(const float2*)(wsl + 4 * l5 + 2);
  f32x2 wfa = mk2(SCLN * wfa0.x, SCLN * wfa0.y), wfb = mk2(SCLN * wfb0.x, SCLN * wfb0.y);
  f32x2 wsa = mk2(SCLP * wsa0.x, SCLP * wsa0.y), wsb = mk2(SCLP * wsb0.x, SCLP * wsb0.y);
  unsigned pd1 = Pd128c[nu];
  float bfc8 = u2f(pd1 << 16), bsc8 = u2f(pd1 & 0xffff0000u);
  float wfc8 = SCLN * wfl[128], wsc8 = SCLP * wsl[128];
  int m = cnt[nu];
  if (m > CAP) m = CAP;
  const int4* cb4 = (const int4*)(csr + (size_t)nu * CAP);  // wave-uniform pair load
  const uint4* Pfq = (const uint4*)Pfs;
  f32x2 accA = (f32x2)0.0f, accB = (f32x2)0.0f;

#define GATHER(qq) Pfq[(size_t)(half ? qq.z : qq.x) * 32 + l5]
#define COMPUTE(qq, gg)                                                       \
  {                                                                           \
    f32x2 ea_ = (f32x2)__int_as_float(half ? qq.w : qq.y);                    \
    edge_ch2(__builtin_elementwise_fma(ea_, wfa, bfa + unp(gg.x)),            \
             __builtin_elementwise_fma(ea_, wsa, bsa + unp(gg.y)), accA);     \
    edge_ch2(__builtin_elementwise_fma(ea_, wfb, bfb + unp(gg.z)),            \
             __builtin_elementwise_fma(ea_, wsb, bsb + unp(gg.w)), accB);     \
  }

  int Pf = m >> 1;
  int4 qc = make_int4(0, 0, 0, 0);
  uint4 gc = make_uint4(0, 0, 0, 0);
  if (Pf > 0) {
    qc = cb4[0];
    gc = GATHER(qc);
  }
  for (int p = 0; p < Pf; ++p) {
    int4 qn = qc;
    uint4 gn = gc;
    if (p + 1 < Pf) {
      qn = cb4[p + 1];
      gn = GATHER(qn);
    }
    COMPUTE(qc, gc);
    qc = qn;
    gc = gn;
  }
  if ((m & 1) && half == 0) {  // last edge: only half 0 computes it (exec-masked)
    int4 qt = cb4[Pf];
    f32x2 ea_ = (f32x2)__int_as_float(qt.y);
    uint4 gt = Pfq[(size_t)qt.x * 32 + l5];
    edge_ch2(__builtin_elementwise_fma(ea_, wfa, bfa + unp(gt.x)),
             __builtin_elementwise_fma(ea_, wsa, bsa + unp(gt.y)), accA);
    edge_ch2(__builtin_elementwise_fma(ea_, wfb, bfb + unp(gt.z)),
             __builtin_elementwise_fma(ea_, wsb, bsb + unp(gt.w)), accB);
  }
#undef GATHER
#undef COMPUTE

  // combine halves
  accA.x += __shfl_xor(accA.x, 32, 64);
  accA.y += __shfl_xor(accA.y, 32, 64);
  accB.x += __shfl_xor(accB.x, 32, 64);
  accB.y += __shfl_xor(accB.y, 32, 64);

  // channel 128: lanes parallel over edges (deg <= 64), single u32 gather, reduce
  float v2 = 0.f;
  if (lane < m) {
    int2 se = csr[(size_t)nu * CAP + lane];
    float ea = __int_as_float(se.y);
    unsigned pc = Pc128[se.x];
    float f2 = u2f(pc << 16), s2 = u2f(pc & 0xffff0000u);
    float gf2 = fmaf(ea, wfc8, bfc8 + f2);
    float gs2 = fmaf(ea, wsc8, bsc8 + s2);
    float sp2 = LG2(1.0f + EX2(-fabsf(gs2))) + fmaxf(gs2, 0.0f);
    v2 = C693 * fast_rcp(1.0f + EX2(gf2)) * sp2;
  }
#pragma unroll
  for (int off = 32; off; off >>= 1) v2 += __shfl_down(v2, off, 64);

  if (half == 0) {
    uint2 xv = *(const uint2*)(xbu + (size_t)nu * 64 + 2 * l5);
    f32x2 xa = __builtin_elementwise_fma(accA, (f32x2)C693, unp(xv.x));
    f32x2 xb = __builtin_elementwise_fma(accB, (f32x2)C693, unp(xv.y));
    *(uint2*)(xbu + (size_t)nu * 64 + 2 * l5) =
        make_uint2(pkbfr(xa.x, xa.y), pkbfr(xb.x, xb.y));
  }
  if (lane == 0) x128c[nu] += v2;
}

// 4 partial blocks per graph, disjoint writes (no atomics, no pre-zero)
__global__ void pool2(const unsigned* __restrict__ xbu, const float* __restrict__ x128c,
                      const int* __restrict__ goff, float* __restrict__ gpart) {
  int gph = blockIdx.x >> 2;
  int q = blockIdx.x & 3;
  int t = threadIdx.x;
  if (t >= 129) return;
  int s = goff[gph], e = goff[gph + 1];
  int len = e - s;
  int chunk = (len + 3) >> 2;
  int a = s + q * chunk;
  int b = a + chunk; if (b > e) b = e;
  float acc = 0.f;
  if (t < 128) {
    int w = t >> 1, hi = t & 1;
    for (int n = a; n < b; ++n) {
      unsigned u = xbu[(size_t)n * 64 + w];
      acc += hi ? u2f(u & 0xffff0000u) : u2f(u << 16);
    }
  } else {
    for (int n = a; n < b; ++n) acc += x128c[n];
  }
  gpart[(size_t)(gph * 4 + q) * 132 + t] = acc;  // unconditional (ws is poisoned)
}

// fused: partial-sum + mean-divide + fc1 + fc2 + fc3 + out. one block per graph.
// [R16] double-buffered 16-wide independent W loads — was 75us serial-chain, theory
// confirmed (dropped out of top-5).
__global__ void fcout(const float* __restrict__ gpart, const int* __restrict__ goff,
                      const float* __restrict__ Wfc, const float* __restrict__ bfc,
                      const float* __restrict__ Wout, const float* __restrict__ bout,
                      float* __restrict__ out) {
  __shared__ float buf[2][132];
  __shared__ float red[3];
  int i = blockIdx.x;
  int t = threadIdx.x;
  bool act = t < 129;
  int len = goff[i + 1] - goff[i];
  float inv = fast_rcp(fmaxf((float)len, 1.0f));
  if (act) {
    float v = gpart[(size_t)(i * 4 + 0) * 132 + t] + gpart[(size_t)(i * 4 + 1) * 132 + t] +
              gpart[(size_t)(i * 4 + 2) * 132 + t] + gpart[(size_t)(i * 4 + 3) * 132 + t];
    buf[0][t] = v * inv;
  }
  __syncthreads();
  int cur = 0;
#pragma unroll
  for (int l = 0; l < 3; ++l) {
    float s = 0.f;
    if (act) {
      const float* Wl = Wfc + (size_t)l * 129 * 129 + t;
      s = bfc[l * 129 + t];
      float wA[16], wB[16];
      float wlast = Wl[(size_t)128 * 129];  // k=128 tail, issued early
#pragma unroll
      for (int j = 0; j < 16; ++j) wA[j] = Wl[(size_t)j * 129];  // group 0
#pragma unroll
      for (int kb = 0; kb < 128; kb += 16) {
        const int gidx = kb >> 4;  // compile-time under unroll
        float* wc = (gidx & 1) ? wB : wA;
        float* wn = (gidx & 1) ? wA : wB;
        if (kb + 16 < 128) {
#pragma unroll
          for (int j = 0; j < 16; ++j) wn[j] = Wl[(size_t)(kb + 16 + j) * 129];
        }
#pragma unroll
        for (int j = 0; j < 16; ++j) s = fmaf(buf[cur][kb + j], wc[j], s);
      }
      s = fmaf(buf[cur][128], wlast, s);
    }
    __syncthreads();
    if (act) buf[1 - cur][t] = s;
    cur = 1 - cur;
    __syncthreads();
  }
  float p = act ? buf[cur][t] * Wout[t] : 0.f;
#pragma unroll
  for (int off = 32; off; off >>= 1) p += __shfl_down(p, off, 64);
  if ((t & 63) == 0) red[t >> 6] = p;
  __syncthreads();
  if (t == 0) out[i] = red[0] + red[1] + red[2] + bout[0];
}

extern "C" void kernel_launch(void* const* d_in, const int* in_sizes, int n_in,
                              void* d_out, int out_size, void* d_ws, size_t ws_size,
                              hipStream_t stream) {
  const int* atoms = (const int*)d_in[0];
  const float* pos = (const float*)d_in[1];
  const int* ei = (const int*)d_in[2];
  const int* batch = (const int*)d_in[3];
  const float* emb = (const float*)d_in[4];
  const float* Wf = (const float*)d_in[5];
  const float* bfp = (const float*)d_in[6];
  const float* Ws = (const float*)d_in[7];
  const float* bsp = (const float*)d_in[8];
  const float* Wfc = (const float*)d_in[9];
  const float* bfc = (const float*)d_in[10];
  const float* Wout = (const float*)d_in[11];
  const float* bout = (const float*)d_in[12];
  float* outp = (float*)d_out;

  // workspace layout (every array 16B-aligned by construction)
  uint4* Bp = (uint4*)d_ws;                                   // 46080 uint4
  unsigned* xbu = (unsigned*)(Bp + 46080);                    // NPADROWS*64 u32
  unsigned short* Pdh = (unsigned short*)(xbu + (size_t)NPADROWS * 64);  // NPADROWS*256
  unsigned short* Pfs = Pdh + (size_t)NPADROWS * 256;         // NPADROWS*256
  float4* pos4 = (float4*)(Pfs + (size_t)NPADROWS * 256);     // N_NODES float4
  float2* Wtail = (float2*)(pos4 + N_NODES);                  // 5*4*144 float2
  float* x128c = (float*)(Wtail + 5 * 4 * 144);               // NPADROWS f32
  float* gpart = x128c + NPADROWS;                            // 256*4*132 f32
  int* goff = (int*)(gpart + 256 * 4 * 132);                  // 260 (padded)
  int* cnt = goff + 260;                                      // N_NODES (+pad)
  int2* csr = (int2*)(cnt + N_NODES + 4);                     // N_NODES*CAP (16B-aligned)
  unsigned* Pd128c = (unsigned*)(csr + (size_t)N_NODES * CAP);  // NPADROWS u32
  unsigned* Pc128 = Pd128c + NPADROWS;                        // NPADROWS u32
  int* perm = (int*)(Pc128 + NPADROWS);                       // N_NODES (degree-sorted)
  int* bcnt = perm + N_NODES;                                 // NHB*65 per-block hist
  int* boff = bcnt + NHB * (CAP + 1);                         // NHB*65 scatter bases

  init_x<<<(N_NODES + 3) / 4, 256, 0, stream>>>(atoms, pos, emb, x128c, xbu, pos4, cnt);
  prep_b<<<(5 * 4 * 9 * 4 * 64 + 5 * 4 * 144 + 255) / 256, 256, 0, stream>>>(
      Wf, Ws, bfp, bsp, Bp, Wtail);
  build_csr<<<(N_EDGES + 255) / 256, 256, 0, stream>>>(ei, pos4, batch, cnt, csr, goff);
  deg_hist_blk<<<NHB, 256, 0, stream>>>(cnt, bcnt);
  deg_off<<<1, 128, 0, stream>>>(bcnt, boff);
  deg_scatter_blk<<<NHB, 256, 0, stream>>>(cnt, boff, perm);

  for (int l = 0; l < 5; ++l) {
    gemm_mfma<<<NPADROWS / 32, 256, 0, stream>>>(xbu, x128c, Bp, Wtail, Pdh, Pfs,
                                                 Pd128c, Pc128, l);
    edge_agg<<<(N_NODES + 3) / 4, 256, 0, stream>>>(Pdh, Pfs, Pd128c, Pc128, xbu, x128c,
                                                    cnt, csr,
                                                    Wf + (size_t)l * 259 * 129,
                                                    Ws + (size_t)l * 259 * 129, perm);
  }

  pool2<<<NUM_GRAPHS * 4, 192, 0, stream>>>(xbu, x128c, goff, gpart);
  fcout<<<NUM_GRAPHS, 192, 0, stream>>>(gpart, goff, Wfc, bfc, Wout, bout, outp);
}

// Round 10
// 617.379 us; speedup vs baseline: 1.0238x; 1.0010x over previous
//
#include <hip/hip_runtime.h>
#include <math.h>

#define N_NODES 50000
#define N_EDGES 800000
#define NUM_GRAPHS 256
#define NPADROWS 50048   // 1564*32
#define CAP 64           // CSR capacity per node (max observed degree ~35)
#define NHB 64           // counting-sort blocks
#define DCH ((N_NODES + NHB - 1) / NHB)  // nodes per sort block (782)
#define SCLN -1.44269504088896f  // -log2(e): f-side scale, exp2(SCLN*x)=exp(-x)
#define SCLP 1.44269504088896f   // +log2(e): s-side scale
#define C693 0.69314718056f
#define LROW 264         // LDS staging row stride in u16 (528 B)

typedef __attribute__((ext_vector_type(8))) short short8;
typedef __attribute__((ext_vector_type(4))) float f32x4;
typedef __attribute__((ext_vector_type(2))) float f32x2;

__device__ __forceinline__ float fast_rcp(float x) {
#if __has_builtin(__builtin_amdgcn_rcpf)
  return __builtin_amdgcn_rcpf(x);
#else
  return 1.0f / x;
#endif
}
__device__ __forceinline__ float EX2(float x) {
#if __has_builtin(__builtin_amdgcn_exp2f)
  return __builtin_amdgcn_exp2f(x);
#else
  return exp2f(x);
#endif
}
__device__ __forceinline__ float LG2(float x) {
#if __has_builtin(__builtin_amdgcn_logf)
  return __builtin_amdgcn_logf(x);  // log2
#else
  return log2f(x);
#endif
}
// round-to-nearest-even (prep path, cold)
__device__ __forceinline__ unsigned f2bf(float x) {
  unsigned u = __float_as_uint(x);
  return (u + 0x7fffu + ((u >> 16) & 1u)) >> 16;
}
// round-half-up bf16: 1 VALU op
__device__ __forceinline__ unsigned short bfr(float v) {
  return (unsigned short)((__float_as_uint(v) + 0x8000u) >> 16);
}
__device__ __forceinline__ unsigned pkbfr(float lo, float hi) {
  unsigned a = (__float_as_uint(lo) + 0x8000u) >> 16;
  unsigned b = (__float_as_uint(hi) + 0x8000u) & 0xffff0000u;
  return a | b;
}
__device__ __forceinline__ float u2f(unsigned u) { return __uint_as_float(u); }
__device__ __forceinline__ f32x2 mk2(float a, float b) {
  f32x2 r; r.x = a; r.y = b; return r;
}
// unpack u32 holding (lo u16 -> ch0 bf16, hi u16 -> ch1 bf16) to f32x2
__device__ __forceinline__ f32x2 unp(unsigned u) {
  return mk2(u2f(u << 16), u2f(u & 0xffff0000u));
}
// log2(1+t) for t in [0,1], packed f32x2 Horner.
// [R15: trans ~6cy/op on trans pipe — poly vs 2xLG2 ≈ -4us/dispatch; kept.]
__device__ __forceinline__ f32x2 lg2p1(f32x2 t) {
  f32x2 p = __builtin_elementwise_fma(t, (f32x2)0.0439245f, (f32x2)-0.1898214f);
  p = __builtin_elementwise_fma(t, p, (f32x2)0.4115517f);
  p = __builtin_elementwise_fma(t, p, (f32x2)-0.7072504f);
  p = __builtin_elementwise_fma(t, p, (f32x2)1.4415927f);
  return t * p;
}
// msg pair: sigm (exp2 dom, gf pre-scaled -log2e) * softplus (gs pre-scaled +log2e)
// ln2 factor NOT applied here (folded into epilogue pk_fma); acc += rcp(den)*sp_log2.
// Trans budget/pair: 2 EX2 (sigmoid) + 2 EX2 (softplus) + 2 rcp — minimal for
// this math; edge_agg is near its instruction floor [R21/R22 accounting].
__device__ __forceinline__ void edge_ch2(f32x2 gf, f32x2 gs, f32x2& acc) {
  f32x2 den = mk2(EX2(gf.x), EX2(gf.y)) + 1.0f;
  f32x2 ts = mk2(EX2(-fabsf(gs.x)), EX2(-fabsf(gs.y)));
  f32x2 sp = lg2p1(ts) + __builtin_elementwise_max(gs, (f32x2)0.0f);
  f32x2 rc = mk2(fast_rcp(den.x), fast_rcp(den.y));
  acc = __builtin_elementwise_fma(rc, sp, acc);
}

// [R23] 4 nodes per 256-thread block (was 50K single-wave blocks — pure
// dispatch overhead). Same loads/stores per node.
__global__ __launch_bounds__(256) void init_x(
    const int* __restrict__ atoms, const float* __restrict__ pos,
    const float* __restrict__ emb, float* __restrict__ x128c,
    unsigned* __restrict__ xbu, float4* __restrict__ pos4, int* __restrict__ cnt) {
  int n = blockIdx.x * 4 + (threadIdx.x >> 6);
  if (n >= N_NODES) return;
  int t = threadIdx.x & 63;
  int a = atoms[n];
  float2 e = *(const float2*)(emb + (size_t)a * 128 + 2 * t);
  xbu[(size_t)n * 64 + t] = f2bf(e.x) | (f2bf(e.y) << 16);
  if (t == 0) x128c[n] = pos[n * 3 + 2];
  if (t == 1) pos4[n] = make_float4(pos[3 * n], pos[3 * n + 1], pos[3 * n + 2], 0.f);
  if (t == 2) cnt[n] = 0;
}

// B (pre-scaled by SCLN/SCLP) in MFMA fragment order + Wtail (scale*w1, scale*bias).
__global__ void prep_b(const float* __restrict__ Wf, const float* __restrict__ Ws,
                       const float* __restrict__ bfp, const float* __restrict__ bsp,
                       uint4* __restrict__ Bp, float2* __restrict__ Wtail) {
  int idx = blockIdx.x * 256 + threadIdx.x;
  if (idx < 5 * 4 * 9 * 4 * 64) {
    int lane = idx & 63;
    int t = idx >> 6;
    int ks = t & 3; t >>= 2;
    int ct = t % 9; t /= 9;
    int g = t & 3;
    int l = t >> 2;
    const float* W = (g >= 2) ? Ws : Wf;
    float sc = (g < 2) ? SCLN : SCLP;  // scale folded into B -> MFMA acc pre-scaled
    int col = ct * 16 + (lane & 15);
    int kb = ks * 32 + (lane >> 4) * 8;
    unsigned u[4];
#pragma unroll
    for (int p = 0; p < 4; ++p) {
      unsigned lo = 0, hi = 0;
      if (col < 129) {
        int k0 = kb + 2 * p, k1 = k0 + 1;
        int r0 = (g & 1) ? 129 + k0 : k0;
        int r1 = (g & 1) ? 129 + k1 : k1;
        lo = f2bf(sc * W[(size_t)(l * 259 + r0) * 129 + col]);
        hi = f2bf(sc * W[(size_t)(l * 259 + r1) * 129 + col]);
      }
      u[p] = lo | (hi << 16);
    }
    Bp[idx] = make_uint4(u[0], u[1], u[2], u[3]);
  } else {
    int j = idx - 5 * 4 * 9 * 4 * 64;
    if (j >= 5 * 4 * 144) return;
    int c = j % 144;
    int t = j / 144;
    int g = t & 3;
    int l = t >> 2;
    float sc = (g < 2) ? SCLN : SCLP;
    float w1 = 0.0f, bias = 0.0f;
    if (c <= 128) {
      const float* W = (g >= 2) ? Ws : Wf;
      int row = (g & 1) ? 257 : 128;
      w1 = sc * W[(size_t)(l * 259 + row) * 129 + c];
      if (g == 0) bias = SCLN * bfp[l * 129 + c];
      if (g == 2) bias = SCLP * bsp[l * 129 + c];
    }
    Wtail[(l * 4 + g) * 144 + c] = make_float2(w1, bias);
  }
}

// edge CSR build; threads <= N_NODES also emit graph offsets
__global__ void build_csr(const int* __restrict__ ei, const float4* __restrict__ pos4,
                          const int* __restrict__ batch, int* __restrict__ cnt,
                          int2* __restrict__ csr, int* __restrict__ goff) {
  int e = blockIdx.x * 256 + threadIdx.x;
  if (e <= N_NODES) {
    int b = (e < N_NODES) ? batch[e] : NUM_GRAPHS;
    int bp = (e > 0) ? batch[e - 1] : -1;
    for (int g = bp + 1; g <= b; ++g) goff[g] = e;
  }
  if (e >= N_EDGES) return;
  int s = ei[e];
  int d = ei[N_EDGES + e];
  float4 ps = pos4[s];
  float4 pd = pos4[d];
  float dx = ps.x - pd.x, dy = ps.y - pd.y, dz = ps.z - pd.z;
  float ea = sqrtf(dx * dx + dy * dy + dz * dz);
  int p = atomicAdd(&cnt[d], 1);
  if (p < CAP) csr[d * CAP + p] = make_int2(s, __float_as_int(ea));
}

// [R21] counting sort with ZERO global atomics (R20's 50K device-atomics into
// 2 cache lines was 145us of RMW serialization). Confirmed fixed: deg_* gone
// from top-5; edge_agg 76->72.4us, occupancy 66->75%.
__global__ void deg_hist_blk(const int* __restrict__ cnt, int* __restrict__ bcnt) {
  __shared__ int sh[CAP + 1];
  int t = threadIdx.x, b = blockIdx.x;
  if (t <= CAP) sh[t] = 0;
  __syncthreads();
  int a = b * DCH, e = a + DCH;
  if (e > N_NODES) e = N_NODES;
  for (int n = a + t; n < e; n += 256) {
    int d = cnt[n]; if (d > CAP) d = CAP;
    atomicAdd(&sh[d], 1);  // LDS atomic — contention-free at this scale
  }
  __syncthreads();
  if (t <= CAP) bcnt[b * (CAP + 1) + t] = sh[t];
}
// thread d: register-unrolled prefix over NHB blocks (static indices — no
// scratch, loads issue independently) + shared suffix-sum across bins so
// DESCENDING degree gets the low perm slots (long waves launch first).
__global__ void deg_off(const int* __restrict__ bcnt, int* __restrict__ boff) {
  __shared__ int tot[CAP + 1];
  int d = threadIdx.x;
  int c[NHB];
  if (d <= CAP) {
#pragma unroll
    for (int b = 0; b < NHB; ++b) c[b] = bcnt[b * (CAP + 1) + d];
    int run = 0;
#pragma unroll
    for (int b = 0; b < NHB; ++b) { int v = c[b]; c[b] = run; run += v; }
    tot[d] = run;
  }
  __syncthreads();
  if (d <= CAP) {
    int gbase = 0;
    for (int dd = d + 1; dd <= CAP; ++dd) gbase += tot[dd];
#pragma unroll
    for (int b = 0; b < NHB; ++b) boff[b * (CAP + 1) + d] = c[b] + gbase;
  }
}
__global__ void deg_scatter_blk(const int* __restrict__ cnt,
                                const int* __restrict__ boff, int* __restrict__ perm) {
  __shared__ int base[CAP + 1];
  int t = threadIdx.x, b = blockIdx.x;
  if (t <= CAP) base[t] = boff[b * (CAP + 1) + t];
  __syncthreads();
  int a = b * DCH, e = a + DCH;
  if (e > N_NODES) e = N_NODES;
  for (int n = a + t; n < e; n += 256) {
    int d = cnt[n]; if (d > CAP) d = CAP;
    int pos = atomicAdd(&base[d], 1);  // LDS atomic
    perm[pos] = n;
  }
}

// [R23 = exact R19 revert: 4 waves/256 thr. R22's 8-wave split regressed
// (+1.5us/layer: guard-masked MFMAs, doubled barrier contention, LDS still
// caps residency at 3 blocks/CU). R17/R18 operand-swap also lost. This
// structure is the empirical local optimum: ~36us/layer (B-latency ~2.6
// [R19 delta], HBM r+w floor ~12, rest = barrier+epilogue serial structure).]
// 32 rows x (4 groups x 144 cols) per block; wave w = group w.
// u16 row layout (256 u16): [f(2c),f(2c+1),s(2c),s(2c+1)] at c*4 — Pdh dst, Pfs src.
__global__ __launch_bounds__(256) void gemm_mfma(
    const unsigned* __restrict__ xbu, const float* __restrict__ x128c,
    const uint4* __restrict__ Bp, const float2* __restrict__ Wtail,
    unsigned short* __restrict__ Pdh, unsigned short* __restrict__ Pfs,
    unsigned* __restrict__ Pd128c, unsigned* __restrict__ Pc128, int layer) {
  __shared__ short smA[32 * 136];             // A staging, row stride 136 shorts
  __shared__ unsigned short ldsD[32 * LROW];  // dst row image (f+s interleaved)
  __shared__ unsigned short ldsS[32 * LROW];  // src row image
  int n0 = blockIdx.x * 32;
  int tid = threadIdx.x;
  int g = tid >> 6;
  int l = tid & 63;
  int q = l >> 4, c16 = l & 15;
  const short8* Bp8 = (const short8*)Bp;
  const short8* Bq = Bp8 + (size_t)((layer * 4 + g) * 36) * 64 + l;

  // staging loads + ks=0 fragment batch issued back-to-back: the 9 frag loads
  // fly during the smA ds_writes and the barrier.
  int row0 = tid >> 4, cq = tid & 15;
  uint4 st0 = *(const uint4*)(xbu + (size_t)(n0 + row0) * 64 + cq * 4);
  uint4 st1 = *(const uint4*)(xbu + (size_t)(n0 + 16 + row0) * 64 + cq * 4);
  short8 b[9];
#pragma unroll
  for (int ct = 0; ct < 9; ++ct) b[ct] = Bq[(size_t)(ct * 4) * 64];
  *(uint4*)(&smA[row0 * 136 + cq * 8]) = st0;
  *(uint4*)(&smA[(16 + row0) * 136 + cq * 8]) = st1;
  __syncthreads();

  f32x4 acc[2][9];
#pragma unroll
  for (int rt = 0; rt < 2; ++rt)
#pragma unroll
    for (int ct = 0; ct < 9; ++ct) acc[rt][ct] = (f32x4){0.f, 0.f, 0.f, 0.f};
#pragma unroll
  for (int ks = 0; ks < 4; ++ks) {
    short8 a0 = *(const short8*)(&smA[c16 * 136 + (ks * 4 + q) * 8]);
    short8 a1 = *(const short8*)(&smA[(16 + c16) * 136 + (ks * 4 + q) * 8]);
    short8 bn[9];
    if (ks < 3) {
#pragma unroll
      for (int ct = 0; ct < 9; ++ct) bn[ct] = Bq[(size_t)(ct * 4 + ks + 1) * 64];
    }
#pragma unroll
    for (int ct = 0; ct < 9; ++ct) {
      acc[0][ct] = __builtin_amdgcn_mfma_f32_16x16x32_bf16(a0, b[ct], acc[0][ct], 0, 0, 0);
      acc[1][ct] = __builtin_amdgcn_mfma_f32_16x16x32_bf16(a1, b[ct], acc[1][ct], 0, 0, 0);
    }
    if (ks < 3) {
#pragma unroll
      for (int ct = 0; ct < 9; ++ct) b[ct] = bn[ct];
    }
  }
  const float2* Wt = Wtail + (layer * 4 + g) * 144;
  float x128[2][4];
#pragma unroll
  for (int rt = 0; rt < 2; ++rt)
#pragma unroll
    for (int r = 0; r < 4; ++r)
      x128[rt][r] = x128c[n0 + rt * 16 + q * 4 + r];  // contiguous, L1-hit
  unsigned short* ldsO = (g & 1) ? ldsS : ldsD;
  int soff = (g >= 2) ? 2 : 0;
  unsigned short* c128p = (g & 1) ? (unsigned short*)Pc128 : (unsigned short*)Pd128c;
  int c128o = (g >= 2) ? 1 : 0;
#pragma unroll
  for (int ct = 0; ct < 9; ++ct) {
    int col = ct * 16 + c16;
    float2 wb = Wt[col];  // (scale*w1, scale*bias)
#pragma unroll
    for (int rt = 0; rt < 2; ++rt) {
#pragma unroll
      for (int r = 0; r < 4; ++r) {
        int rl = rt * 16 + q * 4 + r;  // local row
        float v = acc[rt][ct][r] + fmaf(x128[rt][r], wb.x, wb.y);
        if (col < 128) {
          ldsO[rl * LROW + ((col >> 1) << 2) + soff + (col & 1)] = bfr(v);
        } else if (col == 128) {
          c128p[2 * (size_t)(n0 + rl) + c128o] = bfr(v);
        }
      }
    }
  }
  __syncthreads();
  // coalesced writeback: 2048 16B-chunks (1024 per image), 8 rounds of 256 thr
#pragma unroll
  for (int i = tid; i < 2048; i += 256) {
    int img = i >> 10;
    int c = i & 1023;
    int row = c >> 5, part = c & 31;
    const unsigned short* src = (img ? ldsS : ldsD) + row * LROW + part * 8;
    unsigned short* dst = (img ? Pfs : Pdh) + (size_t)(n0 + row) * 256 + part * 8;
    *(uint4*)dst = *(const uint4*)src;
  }
}

// one wave per dst node (node = perm[wave] — degree-bucketed, R20/R21). Lanes
// 0-31: even edges, 32-63: odd edges; each lane 4 channels via one uint4 gather.
// Depth-1 prefetch [R13 optimum]. Residual carried in bf16 xbu.
// [R15] LG2 -> packed deg-5 poly; ln2 folded into epilogue fma; exec-masked odd tail.
// [R21/R22 accounting: ~345 busy-cy/iter, of which ~145cy is the 24 trans-pipe
// ops (6 EX2/rcp per channel-pair = math minimum) — near structure floor.
// FETCH 215MB ≈ 8 XCD x 25.6MB Pfs streaming floor for a random graph.]
__global__ __launch_bounds__(256) void edge_agg(
    const unsigned short* __restrict__ Pdh, const unsigned short* __restrict__ Pfs,
    const unsigned* __restrict__ Pd128c, const unsigned* __restrict__ Pc128,
    unsigned* __restrict__ xbu, float* __restrict__ x128c, const int* __restrict__ cnt,
    const int2* __restrict__ csr, const float* __restrict__ WfL,
    const float* __restrict__ WsL, const int* __restrict__ perm) {
  int lane = threadIdx.x & 63;
  int half = lane >> 5;
  int l5 = lane & 31;
  int widx = blockIdx.x * 4 + (threadIdx.x >> 6);
  if (widx >= N_NODES) return;
  int nu = __builtin_amdgcn_readfirstlane(perm[widx]);  // wave-uniform -> scalar pipe
  const float* wfl = WfL + 258 * 129;
  const float* wsl = WsL + 258 * 129;
  uint4 pdv = *(const uint4*)(Pdh + (size_t)nu * 256 + 8 * l5);
  f32x2 bfa = unp(pdv.x), bsa = unp(pdv.y), bfb = unp(pdv.z), bsb = unp(pdv.w);
  float2 wfa0 = *(const float2*)(wfl + 4 * l5);
  float2 wfb0 = *(const float2*)(wfl + 4 * l5 + 2);
  float2 wsa0 = *(const float2*)(wsl + 4 * l5);
  float2 wsb0 = *(const float2*)(wsl + 4 * l5 + 2);
  f32x2 wfa = mk2(SCLN * wfa0.x, SCLN * wfa0.y), wfb = mk2(SCLN * wfb0.x, SCLN * wfb0.y);
  f32x2 wsa = mk2(SCLP * wsa0.x, SCLP * wsa0.y), wsb = mk2(SCLP * wsb0.x, SCLP * wsb0.y);
  unsigned pd1 = Pd128c[nu];
  float bfc8 = u2f(pd1 << 16), bsc8 = u2f(pd1 & 0xffff0000u);
  float wfc8 = SCLN * wfl[128], wsc8 = SCLP * wsl[128];
  int m = cnt[nu];
  if (m > CAP) m = CAP;
  const int4* cb4 = (const int4*)(csr + (size_t)nu * CAP);  // wave-uniform pair load
  const uint4* Pfq = (const uint4*)Pfs;
  f32x2 accA = (f32x2)0.0f, accB = (f32x2)0.0f;

#define GATHER(qq) Pfq[(size_t)(half ? qq.z : qq.x) * 32 + l5]
#define COMPUTE(qq, gg)                                                       \
  {                                                                           \
    f32x2 ea_ = (f32x2)__int_as_float(half ? qq.w : qq.y);                    \
    edge_ch2(__builtin_elementwise_fma(ea_, wfa, bfa + unp(gg.x)),            \
             __builtin_elementwise_fma(ea_, wsa, bsa + unp(gg.y)), accA);     \
    edge_ch2(__builtin_elementwise_fma(ea_, wfb, bfb + unp(gg.z)),            \
             __builtin_elementwise_fma(ea_, wsb, bsb + unp(gg.w)), accB);     \
  }

  int Pf = m >> 1;
  int4 qc = make_int4(0, 0, 0, 0);
  uint4 gc = make_uint4(0, 0, 0, 0);
  if (Pf > 0) {
    qc = cb4[0];
    gc = GATHER(qc);
  }
  for (int p = 0; p < Pf; ++p) {
    int4 qn = qc;
    uint4 gn = gc;
    if (p + 1 < Pf) {
      qn = cb4[p + 1];
      gn = GATHER(qn);
    }
    COMPUTE(qc, gc);
    qc = qn;
    gc = gn;
  }
  if ((m & 1) && half == 0) {  // last edge: only half 0 computes it (exec-masked)
    int4 qt = cb4[Pf];
    f32x2 ea_ = (f32x2)__int_as_float(qt.y);
    uint4 gt = Pfq[(size_t)qt.x * 32 + l5];
    edge_ch2(__builtin_elementwise_fma(ea_, wfa, bfa + unp(gt.x)),
             __builtin_elementwise_fma(ea_, wsa, bsa + unp(gt.y)), accA);
    edge_ch2(__builtin_elementwise_fma(ea_, wfb, bfb + unp(gt.z)),
             __builtin_elementwise_fma(ea_, wsb, bsb + unp(gt.w)), accB);
  }
#undef GATHER
#undef COMPUTE

  // combine halves
  accA.x += __shfl_xor(accA.x, 32, 64);
  accA.y += __shfl_xor(accA.y, 32, 64);
  accB.x += __shfl_xor(accB.x, 32, 64);
  accB.y += __shfl_xor(accB.y, 32, 64);

  // channel 128: lanes parallel over edges (deg <= 64), single u32 gather, reduce
  float v2 = 0.f;
  if (lane < m) {
    int2 se = csr[(size_t)nu * CAP + lane];
    float ea = __int_as_float(se.y);
    unsigned pc = Pc128[se.x];
    float f2 = u2f(pc << 16), s2 = u2f(pc & 0xffff0000u);
    float gf2 = fmaf(ea, wfc8, bfc8 + f2);
    float gs2 = fmaf(ea, wsc8, bsc8 + s2);
    float sp2 = LG2(1.0f + EX2(-fabsf(gs2))) + fmaxf(gs2, 0.0f);
    v2 = C693 * fast_rcp(1.0f + EX2(gf2)) * sp2;
  }
#pragma unroll
  for (int off = 32; off; off >>= 1) v2 += __shfl_down(v2, off, 64);

  if (half == 0) {
    uint2 xv = *(const uint2*)(xbu + (size_t)nu * 64 + 2 * l5);
    f32x2 xa = __builtin_elementwise_fma(accA, (f32x2)C693, unp(xv.x));
    f32x2 xb = __builtin_elementwise_fma(accB, (f32x2)C693, unp(xv.y));
    *(uint2*)(xbu + (size_t)nu * 64 + 2 * l5) =
        make_uint2(pkbfr(xa.x, xa.y), pkbfr(xb.x, xb.y));
  }
  if (lane == 0) x128c[nu] += v2;
}

// [R24] pool2 fused into fcout: 256 blocks x 640 threads. Phase 1 reproduces
// pool2's exact 4-chunk split INSIDE the block (threads 0-511 = chunk q x
// channel ch; threads 512-639 = 4 chunks x 32 lanes for ch128, width-32
// shuffle reduce — all splits at wave boundaries, no intra-wave divergence;
// same per-chunk f32 add order as pool2 -> numerically identical). Kills one
// dispatch + launch gap + the gpart round-trip. xbu is L2/L3-warm from the
// last edge_agg.
__global__ __launch_bounds__(640) void fcout(
    const unsigned* __restrict__ xbu, const float* __restrict__ x128c,
    const int* __restrict__ goff, const float* __restrict__ Wfc,
    const float* __restrict__ bfc, const float* __restrict__ Wout,
    const float* __restrict__ bout, float* __restrict__ out) {
  __shared__ float part[4][132];
  __shared__ float buf[2][132];
  __shared__ float red[10];
  int i = blockIdx.x;
  int t = threadIdx.x;
  int s = goff[i], e = goff[i + 1];
  int len = e - s;
  int chunk = (len + 3) >> 2;
  if (t < 512) {  // 4 chunks x 128 channels (waves 0-7)
    int q = t >> 7, ch = t & 127;
    int w = ch >> 1, hi = ch & 1;
    int a = s + q * chunk, b = a + chunk; if (b > e) b = e;
    float acc = 0.f;
    for (int n = a; n < b; ++n) {
      unsigned u = xbu[(size_t)n * 64 + w];
      acc += hi ? u2f(u & 0xffff0000u) : u2f(u << 16);
    }
    part[q][ch] = acc;
  } else {  // waves 8-9: 4 chunks x 32 lanes for ch128
    int tt = t - 512;
    int q = tt >> 5, l = tt & 31;
    int a = s + q * chunk, b = a + chunk; if (b > e) b = e;
    float acc = 0.f;
    for (int n = a + l; n < b; n += 32) acc += x128c[n];
#pragma unroll
    for (int off = 16; off; off >>= 1) acc += __shfl_down(acc, off, 32);
    if (l == 0) part[q][128] = acc;
  }
  __syncthreads();
  float inv = fast_rcp(fmaxf((float)len, 1.0f));
  bool act = t < 129;
  if (act) buf[0][t] = (part[0][t] + part[1][t] + part[2][t] + part[3][t]) * inv;
  __syncthreads();
  int cur = 0;
#pragma unroll
  for (int l = 0; l < 3; ++l) {
    float sv = 0.f;
    if (act) {
      const float* Wl = Wfc + (size_t)l * 129 * 129 + t;
      sv = bfc[l * 129 + t];
      float wA[16], wB[16];
      float wlast = Wl[(size_t)128 * 129];  // k=128 tail, issued early
#pragma unroll
      for (int j = 0; j < 16; ++j) wA[j] = Wl[(size_t)j * 129];  // group 0
#pragma unroll
      for (int kb = 0; kb < 128; kb += 16) {
        const int gidx = kb >> 4;  // compile-time under unroll
        float* wc = (gidx & 1) ? wB : wA;
        float* wn = (gidx & 1) ? wA : wB;
        if (kb + 16 < 128) {
#pragma unroll
          for (int j = 0; j < 16; ++j) wn[j] = Wl[(size_t)(kb + 16 + j) * 129];
        }
#pragma unroll
        for (int j = 0; j < 16; ++j) sv = fmaf(buf[cur][kb + j], wc[j], sv);
      }
      sv = fmaf(buf[cur][128], wlast, sv);
    }
    __syncthreads();
    if (act) buf[1 - cur][t] = sv;
    cur = 1 - cur;
    __syncthreads();
  }
  float p = act ? buf[cur][t] * Wout[t] : 0.f;
#pragma unroll
  for (int off = 32; off; off >>= 1) p += __shfl_down(p, off, 64);
  if ((t & 63) == 0) red[t >> 6] = p;
  __syncthreads();
  if (t == 0) {
    float r = red[0] + red[1] + red[2];  // waves 3+ carry zeros
    out[i] = r + bout[0];
  }
}

extern "C" void kernel_launch(void* const* d_in, const int* in_sizes, int n_in,
                              void* d_out, int out_size, void* d_ws, size_t ws_size,
                              hipStream_t stream) {
  const int* atoms = (const int*)d_in[0];
  const float* pos = (const float*)d_in[1];
  const int* ei = (const int*)d_in[2];
  const int* batch = (const int*)d_in[3];
  const float* emb = (const float*)d_in[4];
  const float* Wf = (const float*)d_in[5];
  const float* bfp = (const float*)d_in[6];
  const float* Ws = (const float*)d_in[7];
  const float* bsp = (const float*)d_in[8];
  const float* Wfc = (const float*)d_in[9];
  const float* bfc = (const float*)d_in[10];
  const float* Wout = (const float*)d_in[11];
  const float* bout = (const float*)d_in[12];
  float* outp = (float*)d_out;

  // workspace layout (every array 16B-aligned by construction)
  uint4* Bp = (uint4*)d_ws;                                   // 46080 uint4
  unsigned* xbu = (unsigned*)(Bp + 46080);                    // NPADROWS*64 u32
  unsigned short* Pdh = (unsigned short*)(xbu + (size_t)NPADROWS * 64);  // NPADROWS*256
  unsigned short* Pfs = Pdh + (size_t)NPADROWS * 256;         // NPADROWS*256
  float4* pos4 = (float4*)(Pfs + (size_t)NPADROWS * 256);     // N_NODES float4
  float2* Wtail = (float2*)(pos4 + N_NODES);                  // 5*4*144 float2
  float* x128c = (float*)(Wtail + 5 * 4 * 144);               // NPADROWS f32
  float* gpart = x128c + NPADROWS;                            // 256*4*132 f32 (unused, kept for layout)
  int* goff = (int*)(gpart + 256 * 4 * 132);                  // 260 (padded)
  int* cnt = goff + 260;                                      // N_NODES (+pad)
  int2* csr = (int2*)(cnt + N_NODES + 4);                     // N_NODES*CAP (16B-aligned)
  unsigned* Pd128c = (unsigned*)(csr + (size_t)N_NODES * CAP);  // NPADROWS u32
  unsigned* Pc128 = Pd128c + NPADROWS;                        // NPADROWS u32
  int* perm = (int*)(Pc128 + NPADROWS);                       // N_NODES (degree-sorted)
  int* bcnt = perm + N_NODES;                                 // NHB*65 per-block hist
  int* boff = bcnt + NHB * (CAP + 1);                         // NHB*65 scatter bases

  init_x<<<(N_NODES + 3) / 4, 256, 0, stream>>>(atoms, pos, emb, x128c, xbu, pos4, cnt);
  prep_b<<<(5 * 4 * 9 * 4 * 64 + 5 * 4 * 144 + 255) / 256, 256, 0, stream>>>(
      Wf, Ws, bfp, bsp, Bp, Wtail);
  build_csr<<<(N_EDGES + 255) / 256, 256, 0, stream>>>(ei, pos4, batch, cnt, csr, goff);
  deg_hist_blk<<<NHB, 256, 0, stream>>>(cnt, bcnt);
  deg_off<<<1, 128, 0, stream>>>(bcnt, boff);
  deg_scatter_blk<<<NHB, 256, 0, stream>>>(cnt, boff, perm);

  for (int l = 0; l < 5; ++l) {
    gemm_mfma<<<NPADROWS / 32, 256, 0, stream>>>(xbu, x128c, Bp, Wtail, Pdh, Pfs,
                                                 Pd128c, Pc128, l);
    edge_agg<<<(N_NODES + 3) / 4, 256, 0, stream>>>(Pdh, Pfs, Pd128c, Pc128, xbu, x128c,
                                                    cnt, csr,
                                                    Wf + (size_t)l * 259 * 129,
                                                    Ws + (size_t)l * 259 * 129, perm);
  }

  fcout<<<NUM_GRAPHS, 640, 0, stream>>>(xbu, x128c, goff, Wfc, bfc, Wout, bout, outp);
}